// Round 5
// baseline (19397.592 us; speedup 1.0000x reference)
//
#include <hip/hip_runtime.h>
#include <hip/hip_fp16.h>

#define TT   2048
#define EMBD 256
#define HD   256      // H2
#define NG   1024     // 4*H2
#define NC   12
#define NEGV -10000.0f

// recurrence weight split per gate-row: NWv f16 in VGPRs, NTL f16 streamed from L2
#define NWv   160
#define NTL   96      // NWv + NTL == HD
#define NTLD  48      // NTL/2 dwords per row in g_TW

typedef _Float16 half2v __attribute__((ext_vector_type(2)));
typedef unsigned int u16v __attribute__((ext_vector_type(16)));

// ---- static device scratch (zero dependence on d_ws) ----
__device__ float        g_P[2 * TT * NG];       // input-GEMM preactivations (16 MB)
__device__ float        g_HS[2 * TT * HD];      // hidden states both dirs (4 MB)
__device__ float        g_FE[TT * NC];          // CRF emission feats (96 KB)
__device__ unsigned int g_TW[2 * NG * NTLD];    // f16x2 tail weights (384 KB, L2-resident)

// pack two f32 -> two f16 in one dword (one rounding each)
__device__ __forceinline__ unsigned int f2h2(float a, float b) {
  half2v h; h.x = (_Float16)a; h.y = (_Float16)b;
  return __builtin_bit_cast(unsigned int, h);
}
// acc += f32(f16 lo/hi half of w2) * h   (VOP3P v_fma_mix_f32, f32 accumulate)
__device__ __forceinline__ float fmamix_lo(unsigned int w2, float h, float acc) {
  asm("v_fma_mix_f32 %0, %1, %2, %0 op_sel:[0,0,0] op_sel_hi:[1,0,0]"
      : "+v"(acc) : "v"(w2), "v"(h));
  return acc;
}
__device__ __forceinline__ float fmamix_hi(unsigned int w2, float h, float acc) {
  asm("v_fma_mix_f32 %0, %1, %2, %0 op_sel:[1,0,0] op_sel_hi:[1,0,0]"
      : "+v"(acc) : "v"(w2), "v"(h));
  return acc;
}
__device__ __forceinline__ float fsigmoid(float x) { return 1.0f / (1.0f + __expf(-x)); }
__device__ __forceinline__ float ftanh(float x) {
  float a = fabsf(x);
  float e = __expf(-2.0f * a);
  float r = (1.0f - e) / (1.0f + e);
  return copysignf(r, x);
}

// ---------------- K0: pack recurrent tail weights f32 -> f16x2 ----------------
__global__ __launch_bounds__(256) void k_pack(
    const float* __restrict__ WhhF, const float* __restrict__ WhhB)
{
  const int gid = blockIdx.x * 256 + threadIdx.x;   // 2*1024*48 = 98304
  if (gid >= 2 * NG * NTLD) return;
  const int d   = gid / (NG * NTLD);
  const int rem = gid - d * NG * NTLD;
  const int row = rem / NTLD, j = rem - row * NTLD;
  const float* W = d ? WhhB : WhhF;
  const float2 a = *reinterpret_cast<const float2*>(W + (size_t)row * HD + NWv + 2 * j);
  g_TW[gid] = f2h2(a.x, a.y);
}

// ---------------- K1: embedding gather + input GEMM (+ both biases), all f32 ----------------
__global__ __launch_bounds__(256) void k_input(
    const int* __restrict__ sent, const float* __restrict__ emb,
    const float* __restrict__ WihF, const float* __restrict__ bihF,
    const float* __restrict__ bhhF,
    const float* __restrict__ WihB, const float* __restrict__ bihB,
    const float* __restrict__ bhhB)
{
  const int d  = blockIdx.x & 1;
  const int t0 = (blockIdx.x >> 1) * 16;
  const float* Wih = d ? WihB : WihF;
  const float* bih = d ? bihB : bihF;
  const float* bhh = d ? bhhB : bhhF;
  __shared__ float xs[16][EMBD];
  for (int i = threadIdx.x; i < 16 * (EMBD / 4); i += 256) {
    const int tt = i >> 6, e4 = i & 63;
    reinterpret_cast<float4*>(xs[tt])[e4] =
        reinterpret_cast<const float4*>(emb + (size_t)sent[t0 + tt] * EMBD)[e4];
  }
  __syncthreads();
  for (int gg = 0; gg < 4; ++gg) {
    const int g = threadIdx.x + gg * 256;
    const float bias = bih[g] + bhh[g];
    float acc[16];
#pragma unroll
    for (int tt = 0; tt < 16; ++tt) acc[tt] = 0.0f;
    const float* wr = Wih + (size_t)g * EMBD;
    for (int e = 0; e < EMBD; e += 4) {
      const float4 w = *reinterpret_cast<const float4*>(wr + e);
#pragma unroll
      for (int tt = 0; tt < 16; ++tt) {
        acc[tt] += w.x * xs[tt][e] + w.y * xs[tt][e + 1]
                 + w.z * xs[tt][e + 2] + w.w * xs[tt][e + 3];
      }
    }
    float* Pg = g_P + ((size_t)d * TT + t0) * NG + g;
#pragma unroll
    for (int tt = 0; tt < 16; ++tt) Pg[(size_t)tt * NG] = acc[tt] + bias;
  }
}

// ---------------- K2: BiLSTM recurrence — 256 thr/block, 4 gate rows per thread ----------------
// Thread u owns rows {u, 256+u, 512+u, 768+u} = gates i,f,g,o of unit u.
// Per row: NWv f16 in VGPRs (20 x u16v total), NTL f16 streamed from g_TW (L2).
// h: f32 in LDS double buffer; c: thread-local. One barrier per step.
__global__ __launch_bounds__(256, 1) void k_rec(
    const float* __restrict__ WhhF, const float* __restrict__ WhhB,
    const float* __restrict__ h0g, const float* __restrict__ c0g)
{
  __shared__ float hbuf[2 * HD];

  const int d = blockIdx.x;
  const float* Whh = d ? WhhB : WhhF;
  const int u = threadIdx.x;

  // ---- init: VGPR-resident weights f32 -> packed f16 (rows q*256+u, cols 0..NWv) ----
  u16v wv[20];
#pragma unroll
  for (int q = 0; q < 4; ++q) {
    const float* wr = Whh + (size_t)(q * 256 + u) * HD;
#pragma unroll
    for (int v = 0; v < 5; ++v) {
#pragma unroll
      for (int e = 0; e < 16; ++e) {
        const float2 a = *reinterpret_cast<const float2*>(wr + v * 32 + 2 * e);
        wv[q * 5 + v][e] = f2h2(a.x, a.y);
      }
    }
  }
  hbuf[u] = h0g[d * HD + u];            // buffer 0
  float c = c0g[d * HD + u];
  __syncthreads();

  int t = d ? (TT - 1) : 0;
  const int tstep = d ? -1 : 1;
  for (int it = 0; it < TT; ++it, t += tstep) {
    const float* Pt = g_P + ((size_t)d * TT + t) * NG;
    const float p_i = Pt[u];
    const float p_f = Pt[256 + u];
    const float p_g = Pt[512 + u];
    const float p_o = Pt[768 + u];
    const float* hc = hbuf + (it & 1) * HD;

    float aA[4] = {0.f, 0.f, 0.f, 0.f};
    float aB[4] = {0.f, 0.f, 0.f, 0.f};

    // VGPR-resident part: h[0..159]
#pragma unroll
    for (int v = 0; v < 5; ++v) {
#pragma unroll
      for (int k = 0; k < 8; ++k) {
        const float4 hv = *reinterpret_cast<const float4*>(hc + v * 32 + 4 * k);
#pragma unroll
        for (int q = 0; q < 4; ++q) {
          aA[q] = fmamix_lo(wv[q * 5 + v][2 * k],     hv.x, aA[q]);
          aA[q] = fmamix_hi(wv[q * 5 + v][2 * k],     hv.y, aA[q]);
          aB[q] = fmamix_lo(wv[q * 5 + v][2 * k + 1], hv.z, aB[q]);
          aB[q] = fmamix_hi(wv[q * 5 + v][2 * k + 1], hv.w, aB[q]);
        }
      }
    }
    // streamed tail: h[160..255], weights from g_TW (L2-resident)
#pragma unroll
    for (int s = 0; s < 6; ++s) {
      uint4 w4a[4], w4b[4];
#pragma unroll
      for (int q = 0; q < 4; ++q) {
        const uint4* twq = reinterpret_cast<const uint4*>(
            g_TW + ((size_t)d * NG + q * 256 + u) * NTLD + s * 8);
        w4a[q] = twq[0];
        w4b[q] = twq[1];
      }
#pragma unroll
      for (int k = 0; k < 4; ++k) {
        const float4 hv = *reinterpret_cast<const float4*>(hc + NWv + s * 16 + 4 * k);
#pragma unroll
        for (int q = 0; q < 4; ++q) {
          const unsigned int wlo = (k == 0) ? w4a[q].x : (k == 1) ? w4a[q].z
                                 : (k == 2) ? w4b[q].x : w4b[q].z;
          const unsigned int whi = (k == 0) ? w4a[q].y : (k == 1) ? w4a[q].w
                                 : (k == 2) ? w4b[q].y : w4b[q].w;
          aA[q] = fmamix_lo(wlo, hv.x, aA[q]);
          aA[q] = fmamix_hi(wlo, hv.y, aA[q]);
          aB[q] = fmamix_lo(whi, hv.z, aB[q]);
          aB[q] = fmamix_hi(whi, hv.w, aB[q]);
        }
      }
    }

    const float gi = (aA[0] + aB[0]) + p_i;
    const float gf = (aA[1] + aB[1]) + p_f;
    const float gg = (aA[2] + aB[2]) + p_g;
    const float go = (aA[3] + aB[3]) + p_o;

    c = fsigmoid(gf) * c + fsigmoid(gi) * ftanh(gg);
    const float hh = fsigmoid(go) * ftanh(c);
    g_HS[((size_t)d * TT + t) * HD + u] = hh;
    hbuf[((it & 1) ^ 1) * HD + u] = hh;
    __syncthreads();
  }
}

// ---------------- K3: feats = [hf;hb] @ Wlin^T + blin (pure f32) ----------------
__global__ __launch_bounds__(256) void k_feats(
    const float* __restrict__ Wlin, const float* __restrict__ blin)
{
  const int gid = blockIdx.x * 256 + threadIdx.x;
  if (gid >= TT * NC) return;
  const int t = gid / NC, cc = gid - t * NC;
  const float* hf = g_HS + (size_t)t * HD;
  const float* hb = g_HS + ((size_t)TT + t) * HD;
  const float* wr = Wlin + cc * 512;
  float acc = blin[cc];
  for (int j = 0; j < HD; j += 4) {
    const float4 w = *reinterpret_cast<const float4*>(wr + j);
    acc += w.x * hf[j] + w.y * hf[j + 1] + w.z * hf[j + 2] + w.w * hf[j + 3];
  }
  for (int j = 0; j < HD; j += 4) {
    const float4 w = *reinterpret_cast<const float4*>(wr + 256 + j);
    acc += w.x * hb[j] + w.y * hb[j + 1] + w.z * hb[j + 2] + w.w * hb[j + 3];
  }
  g_FE[gid] = acc;
}

// ---------------- K4: Viterbi + backtrace (single wave); f32 in/out ----------------
__global__ __launch_bounds__(64) void k_vit(
    const float* __restrict__ trans, float* __restrict__ out)
{
  const int lane = threadIdx.x;
  const bool act = lane < NC;
  __shared__ unsigned char bp[TT][NC];
  float Trow[NC];
#pragma unroll
  for (int i = 0; i < NC; ++i) Trow[i] = act ? trans[lane * NC + i] : NEGV;
  float fv[NC];
#pragma unroll
  for (int i = 0; i < NC; ++i) fv[i] = (i == 10) ? 0.0f : NEGV;  // START=10

  float f0 = act ? g_FE[lane] : 0.0f;                 // 2-deep FE prefetch
  float f1 = act ? g_FE[NC + lane] : 0.0f;
  for (int t = 0; t < TT; ++t) {
    const float feat = f0;
    f0 = f1;
    f1 = (act && t + 2 < TT) ? g_FE[(t + 2) * NC + lane] : 0.0f;
    float best = fv[0] + Trow[0]; int bi = 0;
#pragma unroll
    for (int i = 1; i < NC; ++i) {
      const float s = fv[i] + Trow[i];
      if (s > best) { best = s; bi = i; }   // strict > == jnp first-max tiebreak
    }
    if (act) bp[t][lane] = (unsigned char)bi;
    const float nf = best + feat;
#pragma unroll
    for (int i = 0; i < NC; ++i) fv[i] = __shfl(nf, i);
  }
  // terminal = fv + transitions[STOP=11] (row 11)
  const float term = act ? (fv[lane] + trans[11 * NC + lane]) : -3.0e38f;
  float tv[NC];
#pragma unroll
  for (int i = 0; i < NC; ++i) tv[i] = __shfl(term, i);
  if (lane == 0) {
    float bs = tv[0]; int bt = 0;
#pragma unroll
    for (int i = 1; i < NC; ++i) if (tv[i] > bs) { bs = tv[i]; bt = i; }
    out[0] = bs;                             // f32 path_score
    int tag = bt;
    for (int t = TT - 1; t >= 0; --t) {
      out[1 + t] = (float)tag;               // path tags as f32
      tag = bp[t][tag];
    }
  }
}

extern "C" void kernel_launch(void* const* d_in, const int* in_sizes, int n_in,
                              void* d_out, int out_size, void* d_ws, size_t ws_size,
                              hipStream_t stream) {
  const int*   sent = (const int*)d_in[0];
  const float* emb  = (const float*)d_in[1];
  const float* WihF = (const float*)d_in[2];
  const float* WhhF = (const float*)d_in[3];
  const float* bihF = (const float*)d_in[4];
  const float* bhhF = (const float*)d_in[5];
  const float* WihB = (const float*)d_in[6];
  const float* WhhB = (const float*)d_in[7];
  const float* bihB = (const float*)d_in[8];
  const float* bhhB = (const float*)d_in[9];
  const float* Wlin = (const float*)d_in[10];
  const float* blin = (const float*)d_in[11];
  const float* h0g  = (const float*)d_in[12];
  const float* c0g  = (const float*)d_in[13];
  const float* trans= (const float*)d_in[14];
  (void)d_ws; (void)ws_size; (void)in_sizes; (void)n_in; (void)out_size;

  k_pack<<<dim3((2 * NG * NTLD + 255) / 256), dim3(256), 0, stream>>>(WhhF, WhhB);

  k_input<<<dim3(2 * (TT / 16)), dim3(256), 0, stream>>>(
      sent, emb, WihF, bihF, bhhF, WihB, bihB, bhhB);

  k_rec<<<dim3(2), dim3(256), 0, stream>>>(WhhF, WhhB, h0g, c0g);

  k_feats<<<dim3((TT * NC + 255) / 256), dim3(256), 0, stream>>>(Wlin, blin);

  k_vit<<<dim3(1), dim3(64), 0, stream>>>(trans, (float*)d_out);
}

// Round 6
// 5633.258 us; speedup vs baseline: 3.4434x; 3.4434x over previous
//
#include <hip/hip_runtime.h>
#include <hip/hip_fp16.h>

#define TT   2048
#define EMBD 256
#define HD   256      // H2
#define NG   1024     // 4*H2
#define NC   12
#define NEGV -10000.0f

// per gate-row (256 f16 = 128 dwords packed): 120 dwords resident in VGPR/AGPR,
// 8 dwords (16 f16) in LDS column-major (conflict-free b32 reads)
#define NRES 120
#define NTAI 8

typedef _Float16 half2v __attribute__((ext_vector_type(2)));

// ---- static device scratch (zero dependence on d_ws) ----
__device__ float g_P[2 * TT * NG];   // input-GEMM preactivations (16 MB)
__device__ float g_HS[2 * TT * HD];  // hidden states both dirs (4 MB)
__device__ float g_FE[TT * NC];      // CRF emission feats (96 KB)

// pack two f32 -> two f16 in one dword (round-to-nearest each)
__device__ __forceinline__ unsigned int f2h2(float a, float b) {
  half2v h; h.x = (_Float16)a; h.y = (_Float16)b;
  return __builtin_bit_cast(unsigned int, h);
}
// acc += w2.x*h2.x + w2.y*h2.y   (v_dot2_f32_f16: f32 accumulate)
__device__ __forceinline__ float fdot2(unsigned int w2, unsigned int h2, float acc) {
  return __builtin_amdgcn_fdot2(__builtin_bit_cast(half2v, w2),
                                __builtin_bit_cast(half2v, h2), acc, false);
}
__device__ __forceinline__ float fsigmoid(float x) { return 1.0f / (1.0f + __expf(-x)); }
__device__ __forceinline__ float ftanh(float x) {
  float a = fabsf(x);
  float e = __expf(-2.0f * a);
  float r = (1.0f - e) / (1.0f + e);
  return copysignf(r, x);
}

// ---------------- K1: embedding gather + input GEMM (+ both biases), all f32 ----------------
__global__ __launch_bounds__(256) void k_input(
    const int* __restrict__ sent, const float* __restrict__ emb,
    const float* __restrict__ WihF, const float* __restrict__ bihF,
    const float* __restrict__ bhhF,
    const float* __restrict__ WihB, const float* __restrict__ bihB,
    const float* __restrict__ bhhB)
{
  const int d  = blockIdx.x & 1;
  const int t0 = (blockIdx.x >> 1) * 16;
  const float* Wih = d ? WihB : WihF;
  const float* bih = d ? bihB : bihF;
  const float* bhh = d ? bhhB : bhhF;
  __shared__ float xs[16][EMBD];
  for (int i = threadIdx.x; i < 16 * (EMBD / 4); i += 256) {
    const int tt = i >> 6, e4 = i & 63;
    reinterpret_cast<float4*>(xs[tt])[e4] =
        reinterpret_cast<const float4*>(emb + (size_t)sent[t0 + tt] * EMBD)[e4];
  }
  __syncthreads();
  for (int gg = 0; gg < 4; ++gg) {
    const int g = threadIdx.x + gg * 256;
    const float bias = bih[g] + bhh[g];
    float acc[16];
#pragma unroll
    for (int tt = 0; tt < 16; ++tt) acc[tt] = 0.0f;
    const float* wr = Wih + (size_t)g * EMBD;
    for (int e = 0; e < EMBD; e += 4) {
      const float4 w = *reinterpret_cast<const float4*>(wr + e);
#pragma unroll
      for (int tt = 0; tt < 16; ++tt) {
        acc[tt] += w.x * xs[tt][e] + w.y * xs[tt][e + 1]
                 + w.z * xs[tt][e + 2] + w.w * xs[tt][e + 3];
      }
    }
    float* Pg = g_P + ((size_t)d * TT + t0) * NG + g;
#pragma unroll
    for (int tt = 0; tt < 16; ++tt) Pg[(size_t)tt * NG] = acc[tt] + bias;
  }
}

// ---------------- K2: BiLSTM recurrence — f16 weights+h, dot2, f32 gates/c ----------------
// 512 threads/block, 1 block/direction. tid<256: rows (u, 512+u) = i,g gates of unit u.
// tid>=256: rows (256+u, 768+u) = f,o gates. h: f16x2 in LDS double buffer.
__global__ __launch_bounds__(512, 2) void k_rec(
    const float* __restrict__ WhhF, const float* __restrict__ WhhB,
    const float* __restrict__ h0g, const float* __restrict__ c0g)
{
  __shared__ unsigned int wt[NTAI * NG];          // 32 KB: tails, column-major wt[j][row]
  __shared__ __align__(16) unsigned int h2[2][HD / 2];  // f16x2 h, double-buffered
  __shared__ float aTerm[HD];                     // sigmoid(i)*tanh(g)

  const int d = blockIdx.x;
  const float* Whh = d ? WhhB : WhhF;
  const int tid = threadIdx.x;
  const int u  = tid & 255;
  const int rA = (tid < 256) ? u : (256 + u);     // i-row or f-row
  const int rB = rA + 512;                        // g-row or o-row

  // ---- init: pack weights f32 -> f16x2 (single rounding) ----
  unsigned int wa[NRES], wb[NRES];
  {
    const float* pA = Whh + (size_t)rA * HD;
    const float* pB = Whh + (size_t)rB * HD;
#pragma unroll
    for (int j = 0; j < NRES; ++j) {
      const float2 a = *reinterpret_cast<const float2*>(pA + 2 * j);
      const float2 b = *reinterpret_cast<const float2*>(pB + 2 * j);
      wa[j] = f2h2(a.x, a.y);
      wb[j] = f2h2(b.x, b.y);
    }
#pragma unroll
    for (int j = 0; j < NTAI; ++j) {
      const float2 a = *reinterpret_cast<const float2*>(pA + 2 * NRES + 2 * j);
      const float2 b = *reinterpret_cast<const float2*>(pB + 2 * NRES + 2 * j);
      wt[j * NG + rA] = f2h2(a.x, a.y);
      wt[j * NG + rB] = f2h2(b.x, b.y);
    }
  }
  if (tid < HD / 2) {
    h2[0][tid] = f2h2(h0g[d * HD + 2 * tid], h0g[d * HD + 2 * tid + 1]);
  }
  float c = 0.0f;
  if (tid >= 256) c = c0g[d * HD + u];
  __syncthreads();

  int t = d ? (TT - 1) : 0;
  const int tstep = d ? -1 : 1;
  for (int it = 0; it < TT; ++it, t += tstep) {
    const float* Pt = g_P + ((size_t)d * TT + t) * NG;
    const float pA_ = Pt[rA];
    const float pB_ = Pt[rB];
    const unsigned int* hc = h2[it & 1];

    float a0 = 0.f, a1 = 0.f, b0 = 0.f, b1 = 0.f;  // 4 chains
#pragma unroll
    for (int j = 0; j < NRES / 4; ++j) {           // 30 iters, 8 h-f16 each
      const uint4 hv = *reinterpret_cast<const uint4*>(hc + 4 * j);
      a0 = fdot2(wa[4 * j + 0], hv.x, a0);
      a1 = fdot2(wa[4 * j + 1], hv.y, a1);
      a0 = fdot2(wa[4 * j + 2], hv.z, a0);
      a1 = fdot2(wa[4 * j + 3], hv.w, a1);
      b0 = fdot2(wb[4 * j + 0], hv.x, b0);
      b1 = fdot2(wb[4 * j + 1], hv.y, b1);
      b0 = fdot2(wb[4 * j + 2], hv.z, b0);
      b1 = fdot2(wb[4 * j + 3], hv.w, b1);
    }
    // tail: h dwords 120..127, weights from LDS column-major (lane-stride-1, no conflicts)
    {
      const uint4 hv0 = *reinterpret_cast<const uint4*>(hc + NRES);
      const uint4 hv1 = *reinterpret_cast<const uint4*>(hc + NRES + 4);
      a0 = fdot2(wt[0 * NG + rA], hv0.x, a0);
      a1 = fdot2(wt[1 * NG + rA], hv0.y, a1);
      a0 = fdot2(wt[2 * NG + rA], hv0.z, a0);
      a1 = fdot2(wt[3 * NG + rA], hv0.w, a1);
      a0 = fdot2(wt[4 * NG + rA], hv1.x, a0);
      a1 = fdot2(wt[5 * NG + rA], hv1.y, a1);
      a0 = fdot2(wt[6 * NG + rA], hv1.z, a0);
      a1 = fdot2(wt[7 * NG + rA], hv1.w, a1);
      b0 = fdot2(wt[0 * NG + rB], hv0.x, b0);
      b1 = fdot2(wt[1 * NG + rB], hv0.y, b1);
      b0 = fdot2(wt[2 * NG + rB], hv0.z, b0);
      b1 = fdot2(wt[3 * NG + rB], hv0.w, b1);
      b0 = fdot2(wt[4 * NG + rB], hv1.x, b0);
      b1 = fdot2(wt[5 * NG + rB], hv1.y, b1);
      b0 = fdot2(wt[6 * NG + rB], hv1.z, b0);
      b1 = fdot2(wt[7 * NG + rB], hv1.w, b1);
    }
    const float gA = (a0 + a1) + pA_;   // i-gate (tid<256) or f-gate
    const float gB = (b0 + b1) + pB_;   // g-gate (tid<256) or o-gate

    if (tid < 256) {
      aTerm[u] = fsigmoid(gA) * ftanh(gB);
    }
    __syncthreads();
    if (tid >= 256) {
      c = fsigmoid(gA) * c + aTerm[u];
      const float hh = fsigmoid(gB) * ftanh(c);
      g_HS[((size_t)d * TT + t) * HD + u] = hh;   // f32 for feats
      reinterpret_cast<unsigned short*>(h2[(it & 1) ^ 1])[u] =
          __half_as_ushort(__float2half(hh));     // f16 recurrent state
    }
    __syncthreads();
  }
}

// ---------------- K3: feats = [hf;hb] @ Wlin^T + blin (pure f32) ----------------
__global__ __launch_bounds__(256) void k_feats(
    const float* __restrict__ Wlin, const float* __restrict__ blin)
{
  const int gid = blockIdx.x * 256 + threadIdx.x;
  if (gid >= TT * NC) return;
  const int t = gid / NC, cc = gid - t * NC;
  const float* hf = g_HS + (size_t)t * HD;
  const float* hb = g_HS + ((size_t)TT + t) * HD;
  const float* wr = Wlin + cc * 512;
  float acc = blin[cc];
  for (int j = 0; j < HD; j += 4) {
    const float4 w = *reinterpret_cast<const float4*>(wr + j);
    acc += w.x * hf[j] + w.y * hf[j + 1] + w.z * hf[j + 2] + w.w * hf[j + 3];
  }
  for (int j = 0; j < HD; j += 4) {
    const float4 w = *reinterpret_cast<const float4*>(wr + 256 + j);
    acc += w.x * hb[j] + w.y * hb[j + 1] + w.z * hb[j + 2] + w.w * hb[j + 3];
  }
  g_FE[gid] = acc;
}

// ---------------- K4: Viterbi + backtrace (single wave); f32 in/out ----------------
__global__ __launch_bounds__(64) void k_vit(
    const float* __restrict__ trans, float* __restrict__ out)
{
  const int lane = threadIdx.x;
  const bool act = lane < NC;
  __shared__ unsigned char bp[TT][NC];
  float Trow[NC];
#pragma unroll
  for (int i = 0; i < NC; ++i) Trow[i] = act ? trans[lane * NC + i] : NEGV;
  float fv[NC];
#pragma unroll
  for (int i = 0; i < NC; ++i) fv[i] = (i == 10) ? 0.0f : NEGV;  // START=10

  float f0 = act ? g_FE[lane] : 0.0f;                 // 2-deep FE prefetch
  float f1 = act ? g_FE[NC + lane] : 0.0f;
  for (int t = 0; t < TT; ++t) {
    const float feat = f0;
    f0 = f1;
    f1 = (act && t + 2 < TT) ? g_FE[(t + 2) * NC + lane] : 0.0f;
    float best = fv[0] + Trow[0]; int bi = 0;
#pragma unroll
    for (int i = 1; i < NC; ++i) {
      const float s = fv[i] + Trow[i];
      if (s > best) { best = s; bi = i; }   // strict > == jnp first-max tiebreak
    }
    if (act) bp[t][lane] = (unsigned char)bi;
    const float nf = best + feat;
#pragma unroll
    for (int i = 0; i < NC; ++i) fv[i] = __shfl(nf, i);
  }
  // terminal = fv + transitions[STOP=11] (row 11)
  const float term = act ? (fv[lane] + trans[11 * NC + lane]) : -3.0e38f;
  float tv[NC];
#pragma unroll
  for (int i = 0; i < NC; ++i) tv[i] = __shfl(term, i);
  if (lane == 0) {
    float bs = tv[0]; int bt = 0;
#pragma unroll
    for (int i = 1; i < NC; ++i) if (tv[i] > bs) { bs = tv[i]; bt = i; }
    out[0] = bs;                             // f32 path_score
    int tag = bt;
    for (int t = TT - 1; t >= 0; --t) {
      out[1 + t] = (float)tag;               // path tags as f32
      tag = bp[t][tag];
    }
  }
}

extern "C" void kernel_launch(void* const* d_in, const int* in_sizes, int n_in,
                              void* d_out, int out_size, void* d_ws, size_t ws_size,
                              hipStream_t stream) {
  const int*   sent = (const int*)d_in[0];
  const float* emb  = (const float*)d_in[1];
  const float* WihF = (const float*)d_in[2];
  const float* WhhF = (const float*)d_in[3];
  const float* bihF = (const float*)d_in[4];
  const float* bhhF = (const float*)d_in[5];
  const float* WihB = (const float*)d_in[6];
  const float* WhhB = (const float*)d_in[7];
  const float* bihB = (const float*)d_in[8];
  const float* bhhB = (const float*)d_in[9];
  const float* Wlin = (const float*)d_in[10];
  const float* blin = (const float*)d_in[11];
  const float* h0g  = (const float*)d_in[12];
  const float* c0g  = (const float*)d_in[13];
  const float* trans= (const float*)d_in[14];
  (void)d_ws; (void)ws_size; (void)in_sizes; (void)n_in; (void)out_size;

  k_input<<<dim3(2 * (TT / 16)), dim3(256), 0, stream>>>(
      sent, emb, WihF, bihF, bhhF, WihB, bihB, bhhB);

  k_rec<<<dim3(2), dim3(512), 0, stream>>>(WhhF, WhhB, h0g, c0g);

  k_feats<<<dim3((TT * NC + 255) / 256), dim3(256), 0, stream>>>(Wlin, blin);

  k_vit<<<dim3(1), dim3(64), 0, stream>>>(trans, (float*)d_out);
}